// Round 4
// baseline (357.570 us; speedup 1.0000x reference)
//
#include <hip/hip_runtime.h>
#include <hip/hip_fp16.h>

#define NN 100000
#define NE 1600000
#define D  64

#define SCAN_BLKS 98        // 98 * 1024 >= NN

typedef __attribute__((ext_vector_type(8))) _Float16 f16x8;
typedef __attribute__((ext_vector_type(4))) float    f32x4;

// ---------- degree count: scattered global atomics on L2-resident deg[] ----------
__global__ __launch_bounds__(256) void k_deg(const int* __restrict__ dst,
                                             int* __restrict__ deg) {
    for (int e = blockIdx.x * 256 + threadIdx.x; e < NE; e += 1024 * 256)
        atomicAdd(&deg[dst[e]], 1);
}

// ---------- scan stage A: per-1024-block exclusive scan + block sums ----------
__global__ __launch_bounds__(1024) void k_scanA(const int* __restrict__ deg,
                                                int* __restrict__ ex,
                                                int* __restrict__ bsum) {
    __shared__ int ps[1024];
    int t = threadIdx.x, b = blockIdx.x;
    int i = b * 1024 + t;
    int v = (i < NN) ? deg[i] : 0;
    ps[t] = v;
    __syncthreads();
    for (int off = 1; off < 1024; off <<= 1) {
        int u = (t >= off) ? ps[t - off] : 0;
        __syncthreads();
        ps[t] += u;
        __syncthreads();
    }
    if (i < NN) ex[i] = ps[t] - v;
    if (t == 1023) bsum[b] = ps[t];
}

// ---------- scan stage B: scan the 98 block sums ----------
__global__ __launch_bounds__(128) void k_scanB(const int* __restrict__ bsum,
                                               int* __restrict__ boff) {
    __shared__ int ps[128];
    int t = threadIdx.x;
    int v = (t < SCAN_BLKS) ? bsum[t] : 0;
    ps[t] = v;
    __syncthreads();
    for (int off = 1; off < 128; off <<= 1) {
        int u = (t >= off) ? ps[t - off] : 0;
        __syncthreads();
        ps[t] += u;
        __syncthreads();
    }
    if (t < SCAN_BLKS) boff[t] = ps[t] - v;
}

// ---------- scan stage C: finalize rs / cur / dinv ----------
__global__ __launch_bounds__(1024) void k_scanC(const int* __restrict__ deg,
                                                const int* __restrict__ ex,
                                                const int* __restrict__ boff,
                                                int* __restrict__ rs,
                                                int* __restrict__ cur,
                                                float* __restrict__ dinv) {
    int b = blockIdx.x;
    int i = b * 1024 + threadIdx.x;
    if (i < NN) {
        int r = ex[i] + boff[b];
        rs[i] = r;
        cur[i] = r;
        int d = deg[i];
        dinv[i] = rsqrtf((float)(d + 1));
        if (i == NN - 1) rs[NN] = r + d;
    }
}

// ---------- scatter: one pass, straight into compact CSR bucket ----------
__global__ __launch_bounds__(256) void k_scatter(const int* __restrict__ src,
                                                 const int* __restrict__ dst,
                                                 int* __restrict__ cur,
                                                 int* __restrict__ bucket) {
    for (int e = blockIdx.x * 256 + threadIdx.x; e < NE; e += 1024 * 256) {
        int d = dst[e];
        int p = atomicAdd(&cur[d], 1);
        bucket[p] = src[e];
    }
}

// ---------- fused MFMA GEMMs: blocks [0,half): g = half(x@Wg * dinv)
//                              blocks [half,2*half): out = pos@Wp + bg + bp ----------
__global__ __launch_bounds__(256) void k_mm(
    const float* __restrict__ x, const float* __restrict__ Wg,
    const float* __restrict__ dinv, __half* __restrict__ g,
    const float* __restrict__ pos, const float* __restrict__ Wp,
    const float* __restrict__ bg, const float* __restrict__ bp,
    float* __restrict__ out)
{
    __shared__ __align__(16) _Float16 Wt[64][64];   // Wt[n][k] = W[k][n]
    int t = threadIdx.x;
    int lane = t & 63;
    int wid = t >> 6;
    int half_grid = gridDim.x >> 1;
    bool job2 = blockIdx.x >= half_grid;
    int blk = job2 ? (blockIdx.x - half_grid) : blockIdx.x;
    const float* A = job2 ? pos : x;
    const float* W = job2 ? Wp : Wg;

    // zero-pad row g[NN] (gather's invalid-edge target)
    if (blockIdx.x == 0 && t < 64) g[(long)NN * D + t] = __float2half(0.f);

    for (int i = t; i < 64 * 64; i += 256) {
        int k = i >> 6, n = i & 63;
        Wt[n][k] = (_Float16)W[i];
    }
    __syncthreads();

    int lr = lane & 15;        // A-row / C-col within tile
    int lg = lane >> 4;        // k-group / C-row-group
    int kofs = lg * 8;

    f16x8 b[4][2];             // hoisted B frags: [col-tile][k-tile]
#pragma unroll
    for (int n = 0; n < 4; ++n)
#pragma unroll
        for (int kt = 0; kt < 2; ++kt)
            b[n][kt] = *(const f16x8*)&Wt[n * 16 + lr][kt * 32 + kofs];

    float bsum[4] = {0.f, 0.f, 0.f, 0.f};
    if (job2) {
#pragma unroll
        for (int n = 0; n < 4; ++n) {
            int cc = n * 16 + lr;
            bsum[n] = bg[cc] + bp[cc];
        }
    }

    for (int rb0 = blk * 64; rb0 < NN; rb0 += half_grid * 64) {
        int rb = rb0 + wid * 16;
        int arow = rb + lr;
        int arc = arow < NN ? arow : NN - 1;
        const float4* ap = (const float4*)(A + (long)arc * 64 + kofs);
        float4 p0 = ap[0], p1 = ap[1], p2 = ap[8], p3 = ap[9];
        f16x8 a0, a1;
        a0[0] = (_Float16)p0.x; a0[1] = (_Float16)p0.y;
        a0[2] = (_Float16)p0.z; a0[3] = (_Float16)p0.w;
        a0[4] = (_Float16)p1.x; a0[5] = (_Float16)p1.y;
        a0[6] = (_Float16)p1.z; a0[7] = (_Float16)p1.w;
        a1[0] = (_Float16)p2.x; a1[1] = (_Float16)p2.y;
        a1[2] = (_Float16)p2.z; a1[3] = (_Float16)p2.w;
        a1[4] = (_Float16)p3.x; a1[5] = (_Float16)p3.y;
        a1[6] = (_Float16)p3.z; a1[7] = (_Float16)p3.w;

        f32x4 z = {0.f, 0.f, 0.f, 0.f};
        f32x4 acc[4] = {z, z, z, z};
#pragma unroll
        for (int n = 0; n < 4; ++n) {
            acc[n] = __builtin_amdgcn_mfma_f32_16x16x32_f16(a0, b[n][0], acc[n], 0, 0, 0);
            acc[n] = __builtin_amdgcn_mfma_f32_16x16x32_f16(a1, b[n][1], acc[n], 0, 0, 0);
        }

        int orow0 = rb + lg * 4;
        if (!job2) {
#pragma unroll
            for (int r = 0; r < 4; ++r) {
                int row = orow0 + r;
                if (row < NN) {
                    float di = dinv[row];
#pragma unroll
                    for (int n = 0; n < 4; ++n)
                        g[(long)row * D + n * 16 + lr] = __float2half(acc[n][r] * di);
                }
            }
        } else {
#pragma unroll
            for (int r = 0; r < 4; ++r) {
                int row = orow0 + r;
                if (row < NN) {
#pragma unroll
                    for (int n = 0; n < 4; ++n)
                        out[(long)row * D + n * 16 + lr] = acc[n][r] + bsum[n];
                }
            }
        }
    }
}

// ---------- gather: 16 lanes per node, 4 nodes per wave ----------
// lane = grp*16 + l;  l = f(granule, 0..7) + hs(edge parity / out half)*8
__global__ __launch_bounds__(256) void k_gather(
    const int* __restrict__ rs, const int* __restrict__ bucket,
    const float* __restrict__ dinv, const __half* __restrict__ g,
    float* __restrict__ out)
{
    int lane = threadIdx.x & 63;
    int l    = lane & 15;
    int f    = l & 7;                 // 16B granule within 128B row
    int hs   = l >> 3;                // edge parity; also output half
    int gb   = lane & 48;             // group base lane
    int wv   = (blockIdx.x << 2) + (threadIdx.x >> 6);
    int nw   = gridDim.x << 2;
    const uint4* gq = (const uint4*)g;   // row = 8 uint4 granules (128B aligned)

    for (int n0 = (wv << 2); n0 < NN; n0 += (nw << 2)) {
        int node = n0 + (lane >> 4);                  // NN % 4 == 0: always valid
        int r0 = rs[node], r1 = rs[node + 1];
        int cnt = r1 - r0;
        int maxc = cnt;                               // wave-max over the 4 groups
        maxc = max(maxc, __shfl_xor(maxc, 16));
        maxc = max(maxc, __shfl_xor(maxc, 32));
        float a0 = 0.f, a1 = 0.f, a2 = 0.f, a3 = 0.f;
        float a4 = 0.f, a5 = 0.f, a6 = 0.f, a7 = 0.f;
        for (int base = 0; base < maxc; base += 16) {
            int sl = (base + l < cnt) ? bucket[r0 + base + l] : NN;  // pad -> zero row
            int lim = maxc - base; if (lim > 16) lim = 16;           // wave-uniform
#pragma unroll 4
            for (int c2 = 0; c2 < lim; c2 += 2) {
                int s = __shfl(sl, gb + c2 + hs);
                uint4 u = gq[(long)s * 8 + f];
                __half2 h0 = *(__half2*)&u.x, h1 = *(__half2*)&u.y;
                __half2 h2 = *(__half2*)&u.z, h3 = *(__half2*)&u.w;
                a0 += __low2float(h0); a1 += __high2float(h0);
                a2 += __low2float(h1); a3 += __high2float(h1);
                a4 += __low2float(h2); a5 += __high2float(h2);
                a6 += __low2float(h3); a7 += __high2float(h3);
            }
        }
        // combine the two edge parities (lane bit 3)
        a0 += __shfl_xor(a0, 8); a1 += __shfl_xor(a1, 8);
        a2 += __shfl_xor(a2, 8); a3 += __shfl_xor(a3, 8);
        a4 += __shfl_xor(a4, 8); a5 += __shfl_xor(a5, 8);
        a6 += __shfl_xor(a6, 8); a7 += __shfl_xor(a7, 8);
        // epilogue: all 64 lanes rmw; wave covers 4 consecutive 256B out rows
        float di = dinv[node];
        uint4 u = gq[(long)node * 8 + f];             // self row granule
        __half2 s0 = hs ? *(__half2*)&u.z : *(__half2*)&u.x;
        __half2 s1 = hs ? *(__half2*)&u.w : *(__half2*)&u.y;
        float b0 = hs ? a4 : a0, b1 = hs ? a5 : a1;
        float b2 = hs ? a6 : a2, b3 = hs ? a7 : a3;
        float4* op = (float4*)(out + (long)node * D) + (f * 2 + hs);
        float4 o = *op;
        o.x += (b0 + __low2float(s0)) * di;
        o.y += (b1 + __high2float(s0)) * di;
        o.z += (b2 + __low2float(s1)) * di;
        o.w += (b3 + __high2float(s1)) * di;
        *op = o;
    }
}

extern "C" void kernel_launch(void* const* d_in, const int* in_sizes, int n_in,
                              void* d_out, int out_size, void* d_ws, size_t ws_size,
                              hipStream_t stream) {
    const float* x   = (const float*)d_in[0];
    const int*   ei  = (const int*)d_in[1];   // [2, NE] int32
    const float* pos = (const float*)d_in[2];
    const float* Wg  = (const float*)d_in[3];
    const float* bg  = (const float*)d_in[4];
    const float* Wp  = (const float*)d_in[5];
    const float* bp  = (const float*)d_in[6];
    float* out = (float*)d_out;

    const int* src = ei;
    const int* dst = ei + NE;

    // ws layout (~20.9 MiB):
    //   [0)          g[(NN+1)*D] half  (128B-aligned rows; row NN = zeros)
    //   [12,800,256) bucket[NE] | deg[NN] | ex[NN] | rs[NN+4] | cur[NN]
    //                | dinv[NN] | bsum[128] | boff[128]
    char* Wb = (char*)d_ws;
    __half*   g      = (__half*)Wb;
    int*      bucket = (int*)(Wb + 12800256);
    int*      deg    = bucket + NE;
    int*      ex     = deg + NN;
    int*      rs     = ex + NN;
    int*      cur    = rs + NN + 4;
    float*    dinv   = (float*)(cur + NN);
    int*      bsum   = (int*)(dinv + NN);
    int*      boff   = bsum + 128;

    hipMemsetAsync(deg, 0, NN * sizeof(int), stream);
    hipLaunchKernelGGL(k_deg,     dim3(1024),      dim3(256),  0, stream, dst, deg);
    hipLaunchKernelGGL(k_scanA,   dim3(SCAN_BLKS), dim3(1024), 0, stream, deg, ex, bsum);
    hipLaunchKernelGGL(k_scanB,   dim3(1),         dim3(128),  0, stream, bsum, boff);
    hipLaunchKernelGGL(k_scanC,   dim3(SCAN_BLKS), dim3(1024), 0, stream,
                       deg, ex, boff, rs, cur, dinv);
    hipLaunchKernelGGL(k_scatter, dim3(1024),      dim3(256),  0, stream,
                       src, dst, cur, bucket);
    hipLaunchKernelGGL(k_mm,      dim3(1564),      dim3(256),  0, stream,
                       x, Wg, dinv, g, pos, Wp, bg, bp, out);
    hipLaunchKernelGGL(k_gather,  dim3(2048),      dim3(256),  0, stream,
                       rs, bucket, dinv, g, out);
}